// Round 1
// baseline (587.581 us; speedup 1.0000x reference)
//
#include <hip/hip_runtime.h>

typedef unsigned short u16;
typedef unsigned int   u32;
typedef __bf16 bf16x8 __attribute__((ext_vector_type(8)));
typedef float  f32x4  __attribute__((ext_vector_type(4)));

// Problem constants: B=64, S=D=DK=DV=512
#define BATCH 64
#define SEQ   512
#define BSS   (64 * 512 * 512)   // 16,777,216 elements per output tensor
#define MTOT  (64 * 512)         // 32768 rows for projections

__device__ __forceinline__ u16 f2bf(float f) {
  u32 u = __builtin_bit_cast(u32, f);
  u += 0x7FFFu + ((u >> 16) & 1u);   // round-to-nearest-even
  return (u16)(u >> 16);
}

__device__ __forceinline__ void gl16(const void* g, void* l) {
  __builtin_amdgcn_global_load_lds(
      (__attribute__((address_space(1))) void*)g,
      (__attribute__((address_space(3))) void*)l,
      16, 0, 0);
}

// ---------------------------------------------------------------------------
// fp32 -> bf16 conversion, 8 elements/thread
__global__ __launch_bounds__(256) void cvt_bf16_kernel(
    const float* __restrict__ in, u16* __restrict__ out, int n8) {
  int i = blockIdx.x * 256 + threadIdx.x;
  if (i >= n8) return;
  const float4* p = reinterpret_cast<const float4*>(in) + (size_t)i * 2;
  float4 x = p[0], y = p[1];
  uint4 r;
  r.x = (u32)f2bf(x.x) | ((u32)f2bf(x.y) << 16);
  r.y = (u32)f2bf(x.z) | ((u32)f2bf(x.w) << 16);
  r.z = (u32)f2bf(y.x) | ((u32)f2bf(y.y) << 16);
  r.w = (u32)f2bf(y.z) | ((u32)f2bf(y.w) << 16);
  reinterpret_cast<uint4*>(out)[i] = r;
}

// pack 5 weight matrices (each 512x512 row-major [out,in]) into bf16 concats
__global__ __launch_bounds__(256) void pack_w_kernel(
    const float* __restrict__ wq, const float* __restrict__ wk,
    const float* __restrict__ wv, const float* __restrict__ wpq,
    const float* __restrict__ wpk, u16* __restrict__ wc1, u16* __restrict__ wc2) {
  int i = blockIdx.x * 256 + threadIdx.x;        // 0 .. 5*262144-1
  int which = i >> 18;
  int off = i & 262143;
  const float* src = which == 0 ? wq : which == 1 ? wk : which == 2 ? wv
                   : which == 3 ? wpq : wpk;
  u16 h = f2bf(src[off]);
  if (which < 3) wc1[(size_t)which * 262144 + off] = h;
  else           wc2[(size_t)(which - 3) * 262144 + off] = h;
}

__global__ __launch_bounds__(256) void pack_bias_kernel(
    const float* __restrict__ bq, const float* __restrict__ bk,
    const float* __restrict__ bv, const float* __restrict__ bpq,
    const float* __restrict__ bpk, float* __restrict__ b1, float* __restrict__ b2) {
  int i = blockIdx.x * 256 + threadIdx.x;        // 0..2559
  if (i < 1536) {
    b1[i] = i < 512 ? bq[i] : i < 1024 ? bk[i - 512] : bv[i - 1024];
  } else {
    int j = i - 1536;
    b2[j] = j < 512 ? bpq[j] : bpk[j - 512];
  }
}

// ---------------------------------------------------------------------------
// NT GEMM: C[m,n] = sum_k A[m,k] * B[n,k], bf16 in, fp32 accum.
// Block 256 thr = 4 waves; tile 128x128, BK=32; each wave 64x64 via 4x4
// mfma_f32_16x16x32_bf16. m97 structure: global_load_lds(16B) staging,
// single LDS buffer, 2 barriers per K-step.
// MODE 0: proj1 -> bf16, +bias, cols [0,1536) route to QU/KU/V
// MODE 1: proj2 -> bf16, +bias, cols [0,1024) route to QU+512/KU+512
// MODE 2: score -> f32, v*scale + bias[col]
// MODE 3: bmm   -> f32
template <int MODE>
__global__ __launch_bounds__(256) void gemm_nt(
    const u16* __restrict__ A, const u16* __restrict__ Bm, int K,
    unsigned long sAz, unsigned long sBz,
    u16* __restrict__ U0, u16* __restrict__ U1, u16* __restrict__ U2,
    float* __restrict__ F, unsigned long sFz,
    const float* __restrict__ bias, float scale) {
  __shared__ u16 lsA[128 * 32];
  __shared__ u16 lsB[128 * 32];

  const int t = threadIdx.x;
  const int z = blockIdx.z;
  const int m0 = blockIdx.y * 128;
  const int n0 = blockIdx.x * 128;
  A += (size_t)z * sAz;
  Bm += (size_t)z * sBz;
  if (MODE >= 2) F += (size_t)z * sFz;

  // staging: thread t loads 16B = 8 bf16; linear LDS layout matches
  // wave-uniform-base + lane*16 requirement (no padding).
  const int srow = t >> 2;
  const int scol = (t & 3) * 8;
  const u16* gA0 = A + (size_t)(m0 + srow) * K + scol;
  const u16* gB0 = Bm + (size_t)(n0 + srow) * K + scol;
  const size_t rowskip = (size_t)64 * K;
  u16* lA0 = lsA + t * 8;
  u16* lA1 = lsA + 2048 + t * 8;
  u16* lB0 = lsB + t * 8;
  u16* lB1 = lsB + 2048 + t * 8;

  const int l = t & 63;
  const int w = t >> 6;
  const int wm = (w & 1) * 64;
  const int wn = (w >> 1) * 64;
  const int fr = l & 15;          // A row / B row within 16-tile
  const int fk = (l >> 4) * 8;    // k offset within BK=32

  f32x4 acc[4][4];
#pragma unroll
  for (int i = 0; i < 4; ++i)
#pragma unroll
    for (int j = 0; j < 4; ++j) acc[i][j] = (f32x4){0.f, 0.f, 0.f, 0.f};

  for (int k0 = 0; k0 < K; k0 += 32) {
    gl16(gA0 + k0, lA0);
    gl16(gA0 + rowskip + k0, lA1);
    gl16(gB0 + k0, lB0);
    gl16(gB0 + rowskip + k0, lB1);
    __syncthreads();
    bf16x8 af[4], bfg[4];
#pragma unroll
    for (int mt = 0; mt < 4; ++mt)
      af[mt] = *reinterpret_cast<const bf16x8*>(&lsA[(wm + mt * 16 + fr) * 32 + fk]);
#pragma unroll
    for (int nt = 0; nt < 4; ++nt)
      bfg[nt] = *reinterpret_cast<const bf16x8*>(&lsB[(wn + nt * 16 + fr) * 32 + fk]);
#pragma unroll
    for (int mt = 0; mt < 4; ++mt)
#pragma unroll
      for (int nt = 0; nt < 4; ++nt)
        acc[mt][nt] = __builtin_amdgcn_mfma_f32_16x16x32_bf16(
            af[mt], bfg[nt], acc[mt][nt], 0, 0, 0);
    __syncthreads();
  }

  // C/D layout (m89-verified): col = lane&15, row = (lane>>4)*4 + reg
  const int cr = (l >> 4) * 4;
  const int cc = l & 15;
#pragma unroll
  for (int mt = 0; mt < 4; ++mt) {
#pragma unroll
    for (int nt = 0; nt < 4; ++nt) {
      const int col = n0 + wn + nt * 16 + cc;
#pragma unroll
      for (int r = 0; r < 4; ++r) {
        const int row = m0 + wm + mt * 16 + cr + r;
        float v = acc[mt][nt][r];
        if (MODE == 0) {
          v += bias[col];
          u16 h = f2bf(v);
          const int which = col >> 9, c = col & 511;
          if (which == 0)      U0[(size_t)row * 1024 + c] = h;        // Q -> QU[:, :512]
          else if (which == 1) U1[(size_t)row * 1024 + c] = h;        // K -> KU[:, :512]
          else                 U2[(size_t)row * 512 + c] = h;         // V
        } else if (MODE == 1) {
          v += bias[col];
          u16 h = f2bf(v);
          const int which = col >> 9, c = col & 511;
          if (which == 0) U0[(size_t)row * 1024 + 512 + c] = h;       // Uq -> QU[:, 512:]
          else            U1[(size_t)row * 1024 + 512 + c] = h;       // Uk -> KU[:, 512:]
        } else if (MODE == 2) {
          F[(size_t)row * 512 + col] = v * scale + bias[col];
        } else {
          F[(size_t)row * 512 + col] = v;
        }
      }
    }
  }
}

// ---------------------------------------------------------------------------
// softmax over rows of 512; one wave per row, 8 elems/lane.
// writes fp32 att to attF and bf16 att to attB.
__global__ __launch_bounds__(256) void softmax_kernel(
    const float* __restrict__ logits, float* __restrict__ attF,
    u16* __restrict__ attB) {
  const int row = blockIdx.x * 4 + (threadIdx.x >> 6);
  const int l = threadIdx.x & 63;
  const float* p = logits + (size_t)row * 512 + l * 8;
  float4 a = *reinterpret_cast<const float4*>(p);
  float4 b = *reinterpret_cast<const float4*>(p + 4);
  float v[8] = {a.x, a.y, a.z, a.w, b.x, b.y, b.z, b.w};
  float mx = v[0];
#pragma unroll
  for (int j = 1; j < 8; ++j) mx = fmaxf(mx, v[j]);
#pragma unroll
  for (int s = 32; s > 0; s >>= 1) mx = fmaxf(mx, __shfl_xor(mx, s, 64));
  float sum = 0.f;
#pragma unroll
  for (int j = 0; j < 8; ++j) {
    v[j] = __expf(v[j] - mx);
    sum += v[j];
  }
#pragma unroll
  for (int s = 32; s > 0; s >>= 1) sum += __shfl_xor(sum, s, 64);
  const float inv = 1.0f / sum;
#pragma unroll
  for (int j = 0; j < 8; ++j) v[j] *= inv;
  float* o = attF + (size_t)row * 512 + l * 8;
  float4 oa = {v[0], v[1], v[2], v[3]};
  float4 ob = {v[4], v[5], v[6], v[7]};
  *reinterpret_cast<float4*>(o) = oa;
  *reinterpret_cast<float4*>(o + 4) = ob;
  uint4 r;
  r.x = (u32)f2bf(v[0]) | ((u32)f2bf(v[1]) << 16);
  r.y = (u32)f2bf(v[2]) | ((u32)f2bf(v[3]) << 16);
  r.z = (u32)f2bf(v[4]) | ((u32)f2bf(v[5]) << 16);
  r.w = (u32)f2bf(v[6]) | ((u32)f2bf(v[7]) << 16);
  *reinterpret_cast<uint4*>(attB + (size_t)row * 512 + l * 8) = r;
}

// ---------------------------------------------------------------------------
extern "C" void kernel_launch(void* const* d_in, const int* in_sizes, int n_in,
                              void* d_out, int out_size, void* d_ws,
                              size_t ws_size, hipStream_t stream) {
  const float* sent = (const float*)d_in[0];
  const float* pos  = (const float*)d_in[1];
  // d_in[2] = branch_emb (unused by reference)
  const float* Wq  = (const float*)d_in[3];
  const float* bq  = (const float*)d_in[4];
  const float* Wk  = (const float*)d_in[5];
  const float* bk  = (const float*)d_in[6];
  const float* Wv  = (const float*)d_in[7];
  const float* bv  = (const float*)d_in[8];
  const float* Wpq = (const float*)d_in[9];
  const float* bpq = (const float*)d_in[10];
  const float* Wpk = (const float*)d_in[11];
  const float* bpk = (const float*)d_in[12];
  const float* abias = (const float*)d_in[13];
  float* out = (float*)d_out;

  // ws layout (bytes), total ~271 MB
  char* ws = (char*)d_ws;
  u16* Xs   = (u16*)(ws);                    // 33,554,432  sent bf16 [32768,512]
  u16* Xp   = (u16*)(ws + 33554432ul);       // 33,554,432  pos  bf16
  u16* QU   = (u16*)(ws + 67108864ul);       // 67,108,864  [32768,1024] = Q|Uq
  u16* KU   = (u16*)(ws + 134217728ul);      // 67,108,864  [32768,1024] = K|Uk
  u16* Vb   = (u16*)(ws + 201326592ul);      // 33,554,432  [32768,512]
  u16* attB = (u16*)(ws + 234881024ul);      // 33,554,432  bf16 att
  u16* Wc1  = (u16*)(ws + 268435456ul);      // 1,572,864   [1536,512]
  u16* Wc2  = (u16*)(ws + 270008320ul);      // 1,048,576   [1024,512]
  float* b1 = (float*)(ws + 271056896ul);    // 6,144
  float* b2 = (float*)(ws + 271063040ul);    // 4,096

  float* attF   = out;            // output 0: att_softmax
  float* out2   = out + BSS;      // output 1: bmm result
  float* logits = out + BSS;      // scratch reuse: logits live before bmm

  cvt_bf16_kernel<<<8192, 256, 0, stream>>>(sent, Xs, MTOT * 512 / 8);
  cvt_bf16_kernel<<<8192, 256, 0, stream>>>(pos, Xp, MTOT * 512 / 8);
  pack_w_kernel<<<5120, 256, 0, stream>>>(Wq, Wk, Wv, Wpq, Wpk, Wc1, Wc2);
  pack_bias_kernel<<<10, 256, 0, stream>>>(bq, bk, bv, bpq, bpk, b1, b2);

  // projections: [32768,512] x [N,512]^T
  gemm_nt<0><<<dim3(12, 256, 1), 256, 0, stream>>>(
      Xs, Wc1, 512, 0ul, 0ul, QU, KU, Vb, nullptr, 0ul, b1, 1.0f);
  gemm_nt<1><<<dim3(8, 256, 1), 256, 0, stream>>>(
      Xp, Wc2, 512, 0ul, 0ul, QU, KU, nullptr, nullptr, 0ul, b2, 1.0f);

  // scores: per batch [512,1024] x [512,1024]^T -> logits*(1/32) + bias[t]
  gemm_nt<2><<<dim3(4, 4, BATCH), 256, 0, stream>>>(
      QU, KU, 1024, (unsigned long)SEQ * 1024, (unsigned long)SEQ * 1024,
      nullptr, nullptr, nullptr, logits, (unsigned long)SEQ * SEQ, abias,
      0.03125f);

  softmax_kernel<<<8192, 256, 0, stream>>>(logits, attF, attB);

  // output: per batch att[512,512] x V[512,512]^T
  gemm_nt<3><<<dim3(4, 4, BATCH), 256, 0, stream>>>(
      attB, Vb, 512, (unsigned long)SEQ * SEQ, (unsigned long)SEQ * SEQ,
      nullptr, nullptr, nullptr, out2, (unsigned long)SEQ * SEQ, nullptr, 1.0f);

  (void)in_sizes; (void)n_in; (void)out_size; (void)ws_size;
}